// Round 9
// baseline (157.483 us; speedup 1.0000x reference)
//
#include <hip/hip_runtime.h>
#include <math.h>

#define HIDDEN 128
#define SCALE 0.25f
#define NB_G 391   // gemm blocks per flavor: ceil(782/2) -> exactly 2 tiles/block

typedef __attribute__((ext_vector_type(8))) short short8v;
typedef __attribute__((ext_vector_type(4))) float f32x4;

__device__ __forceinline__ unsigned short f2bf(float f) {
  const unsigned u = __float_as_uint(f);
  const unsigned r = u + 0x7fffu + ((u >> 16) & 1u);   // RNE
  return (unsigned short)(r >> 16);
}
__device__ __forceinline__ unsigned pack_bf2(float a, float b) {
  unsigned r;
  asm("v_cvt_pk_bf16_f32 %0, %1, %2" : "=v"(r) : "v"(a), "v"(b));
  return r;
}
__device__ __forceinline__ float bflo(unsigned u) { return __uint_as_float(u << 16); }
__device__ __forceinline__ float bfhi(unsigned u) { return __uint_as_float(u & 0xffff0000u); }

__device__ __forceinline__ void gload_lds16(const void* g, void* l) {
  __builtin_amdgcn_global_load_lds(
      (const __attribute__((address_space(1))) unsigned*)g,
      (__attribute__((address_space(3))) unsigned*)l, 16, 0, 0);
}

// blocks 0..31: fragment-ordered bf16 weights. blocks 32..79: zero counts+done
// (grid-strided int4) -- replaces hipMemsetAsync (whose fill kernel cost ~40us).
__global__ __launch_bounds__(256) void init_kernel(
    const float* __restrict__ W0, const float* __restrict__ W1,
    const float* __restrict__ W2, const float* __restrict__ W3,
    unsigned short* __restrict__ Wfrag, int* __restrict__ zero_base, int nzero4)
{
  if (blockIdx.x < 32) {
    const int chunk = blockIdx.x * 256 + threadIdx.x;
    const int m = chunk >> 11;
    const int rem = chunk & 2047;
    const int l = rem & 63;
    const int nkk = rem >> 6;
    const int n = nkk >> 2, kk = nkk & 3;
    const float* W = (m == 0) ? W0 : (m == 1) ? W1 : (m == 2) ? W2 : W3;
    const int row = n * 16 + (l & 15);
    const int k0 = kk * 32 + (l >> 4) * 8;
    const float4 v0 = *(const float4*)&W[row * 128 + k0];
    const float4 v1 = *(const float4*)&W[row * 128 + k0 + 4];
    uint4 o;
    o.x = (unsigned)f2bf(v0.x) | ((unsigned)f2bf(v0.y) << 16);
    o.y = (unsigned)f2bf(v0.z) | ((unsigned)f2bf(v0.w) << 16);
    o.z = (unsigned)f2bf(v1.x) | ((unsigned)f2bf(v1.y) << 16);
    o.w = (unsigned)f2bf(v1.z) | ((unsigned)f2bf(v1.w) << 16);
    *(uint4*)&Wfrag[(size_t)chunk * 8] = o;
  } else {
    const int idx4 = (blockIdx.x - 32) * 256 + threadIdx.x;
    if (idx4 < nzero4)
      *(int4*)&zero_base[idx4 * 4] = make_int4(0, 0, 0, 0);
  }
}

__global__ __launch_bounds__(256) void count_kernel(
    const int* __restrict__ ei, int E, int* __restrict__ counts)
{
  const int e = (blockIdx.x * 256 + threadIdx.x) * 4;
  if (e + 4 <= E) {
    const int4 d = *(const int4*)&ei[E + e];
    atomicAdd(&counts[d.x], 1);
    atomicAdd(&counts[d.y], 1);
    atomicAdd(&counts[d.z], 1);
    atomicAdd(&counts[d.w], 1);
  } else {
    for (int k = e; k < E; ++k) atomicAdd(&counts[ei[E + k]], 1);
  }
}

// QKV projection: block = 64-row X tile (shared LDS, dbuf, 1 barrier/tile);
// wave w owns output cols [32w,32w+32): W-frags in 32 VGPR. acc=mfma(W,X):
// C/D row -> W-col (g16*4+r), col -> X-row (r16). Flavors: K / V / Q.
__global__ __launch_bounds__(256, 4) void qkv_gemm_kernel(
    const float* __restrict__ x_src, const float* __restrict__ x_dst,
    const unsigned short* __restrict__ Wfrag,
    const float* __restrict__ bq, const float* __restrict__ bk,
    const float* __restrict__ bv,
    unsigned short* __restrict__ qb, unsigned short* __restrict__ kvb,
    int Nsrc, int Ndst)
{
  __shared__ __align__(16) char Xs[2][16384];
  const int t = threadIdx.x;
  const int l = t & 63, w = t >> 6;
  const int r16 = l & 15, g16 = l >> 4;

  int bid = blockIdx.x;
  const float* X; const float* bias; const unsigned short* wbase;
  unsigned short* out; int ostride, ooff, N;
  if (bid < NB_G)        { X = x_src; bias = bk; wbase = Wfrag + 16384; out = kvb; ostride = 256; ooff = 0;   N = Nsrc; }
  else if (bid < 2*NB_G) { bid -= NB_G;   X = x_src; bias = bv; wbase = Wfrag + 32768; out = kvb; ostride = 256; ooff = 128; N = Nsrc; }
  else                   { bid -= 2*NB_G; X = x_dst; bias = bq; wbase = Wfrag;         out = qb;  ostride = 128; ooff = 0;   N = Ndst; }
  const int ntiles = (N + 63) >> 6;

  short8v wfr[2][4];
  #pragma unroll
  for (int cb = 0; cb < 2; ++cb)
    #pragma unroll
    for (int kk = 0; kk < 4; ++kk)
      wfr[cb][kk] = ((const short8v*)wbase)[((w * 2 + cb) * 4 + kk) * 64 + l];
  float4 bb[2];
  #pragma unroll
  for (int cb = 0; cb < 2; ++cb) bb[cb] = *(const float4*)&bias[w * 32 + cb * 16 + g16 * 4];

  float4 xv[8];
  int tile = bid;
  {  // prologue: stage tile0 -> buf0
    #pragma unroll
    for (int it = 0; it < 8; ++it) {
      const int c = it * 256 + t;
      const int row = c >> 5, fc = (c & 31) << 2;
      const int g = tile * 64 + row;
      xv[it] = make_float4(0.f, 0.f, 0.f, 0.f);
      if (g < N) xv[it] = *(const float4*)&X[(size_t)g * 128 + fc];
    }
    #pragma unroll
    for (int it = 0; it < 8; ++it) {
      const int c = it * 256 + t;
      const int row = c >> 5, b8 = (c & 31) << 3;
      uint2 p;
      p.x = pack_bf2(xv[it].x, xv[it].y);
      p.y = pack_bf2(xv[it].z, xv[it].w);
      *(uint2*)&Xs[0][row * 256 + (b8 ^ ((row & 7) << 4))] = p;
    }
    __syncthreads();
  }

  int cur = 0;
  for (; tile < ntiles; tile += NB_G) {
    const int nt = tile + NB_G;
    if (nt < ntiles) {               // issue next-tile loads early (T14)
      #pragma unroll
      for (int it = 0; it < 8; ++it) {
        const int c = it * 256 + t;
        const int row = c >> 5, fc = (c & 31) << 2;
        const int g = nt * 64 + row;
        xv[it] = make_float4(0.f, 0.f, 0.f, 0.f);
        if (g < N) xv[it] = *(const float4*)&X[(size_t)g * 128 + fc];
      }
    }
    f32x4 acc[4][2];
    #pragma unroll
    for (int rb = 0; rb < 4; ++rb)
      #pragma unroll
      for (int cb = 0; cb < 2; ++cb)
        acc[rb][cb] = (f32x4){bb[cb].x, bb[cb].y, bb[cb].z, bb[cb].w};
    #pragma unroll
    for (int rb = 0; rb < 4; ++rb) {
      const char* ax = &Xs[cur][(rb * 16 + r16) * 256];
      #pragma unroll
      for (int kk = 0; kk < 4; ++kk) {
        const short8v b = *(const short8v*)(ax + (((kk * 32 + g16 * 8) * 2) ^ ((r16 & 7) << 4)));
        acc[rb][0] = __builtin_amdgcn_mfma_f32_16x16x32_bf16(wfr[0][kk], b, acc[rb][0], 0, 0, 0);
        acc[rb][1] = __builtin_amdgcn_mfma_f32_16x16x32_bf16(wfr[1][kk], b, acc[rb][1], 0, 0, 0);
      }
    }
    #pragma unroll
    for (int rb = 0; rb < 4; ++rb) {
      const int g = tile * 64 + rb * 16 + r16;
      if (g < N) {
        unsigned short* orow = out + (size_t)g * ostride + ooff + w * 32;
        #pragma unroll
        for (int cb = 0; cb < 2; ++cb) {
          uint2 o;
          o.x = pack_bf2(acc[rb][cb][0], acc[rb][cb][1]);
          o.y = pack_bf2(acc[rb][cb][2], acc[rb][cb][3]);
          *(uint2*)&orow[cb * 16 + g16 * 4] = o;
        }
      }
    }
    if (nt < ntiles) {
      #pragma unroll
      for (int it = 0; it < 8; ++it) {
        const int c = it * 256 + t;
        const int row = c >> 5, b8 = (c & 31) << 3;
        uint2 p;
        p.x = pack_bf2(xv[it].x, xv[it].y);
        p.y = pack_bf2(xv[it].z, xv[it].w);
        *(uint2*)&Xs[cur ^ 1][row * 256 + (b8 ^ ((row & 7) << 4))] = p;
      }
    }
    __syncthreads();
    cur ^= 1;
  }
}

// Output projection: same structure, bf16 input staged via global_load_lds with
// pre-swizzled SOURCE (linear LDS dest), f32 float4 epilogue.
__global__ __launch_bounds__(256, 4) void out_gemm_kernel(
    const unsigned short* __restrict__ agg, const unsigned short* __restrict__ Wfrag_o,
    const float* __restrict__ bo, float* __restrict__ Y, int N)
{
  __shared__ __align__(16) char Xs[2][16384];
  const int t = threadIdx.x;
  const int l = t & 63, w = t >> 6;
  const int r16 = l & 15, g16 = l >> 4;
  const int ntiles = (N + 63) >> 6;

  short8v wfr[2][4];
  #pragma unroll
  for (int cb = 0; cb < 2; ++cb)
    #pragma unroll
    for (int kk = 0; kk < 4; ++kk)
      wfr[cb][kk] = ((const short8v*)Wfrag_o)[((w * 2 + cb) * 4 + kk) * 64 + l];
  float4 bb[2];
  #pragma unroll
  for (int cb = 0; cb < 2; ++cb) bb[cb] = *(const float4*)&bo[w * 32 + cb * 16 + g16 * 4];

  int tile = blockIdx.x;
  #pragma unroll
  for (int it = 0; it < 4; ++it) {    // prologue issue tile0 -> buf0
    const int c = it * 256 + t;
    const int row = c >> 4, c16 = c & 15;
    gload_lds16((const char*)agg + (size_t)(tile * 64 + row) * 256 + ((c16 * 16) ^ ((row & 7) << 4)),
                &Xs[0][c * 16]);
  }
  int cur = 0;
  for (; tile < ntiles; tile += NB_G) {
    const int nt = tile + NB_G;
    asm volatile("s_waitcnt vmcnt(0)" ::: "memory");
    __builtin_amdgcn_sched_barrier(0);
    __syncthreads();
    if (nt < ntiles) {
      #pragma unroll
      for (int it = 0; it < 4; ++it) {
        const int c = it * 256 + t;
        const int row = c >> 4, c16 = c & 15;
        gload_lds16((const char*)agg + (size_t)(nt * 64 + row) * 256 + ((c16 * 16) ^ ((row & 7) << 4)),
                    &Xs[cur ^ 1][c * 16]);
      }
    }
    f32x4 acc[4][2];
    #pragma unroll
    for (int rb = 0; rb < 4; ++rb)
      #pragma unroll
      for (int cb = 0; cb < 2; ++cb)
        acc[rb][cb] = (f32x4){bb[cb].x, bb[cb].y, bb[cb].z, bb[cb].w};
    #pragma unroll
    for (int rb = 0; rb < 4; ++rb) {
      const char* ax = &Xs[cur][(rb * 16 + r16) * 256];
      #pragma unroll
      for (int kk = 0; kk < 4; ++kk) {
        const short8v b = *(const short8v*)(ax + (((kk * 32 + g16 * 8) * 2) ^ ((r16 & 7) << 4)));
        acc[rb][0] = __builtin_amdgcn_mfma_f32_16x16x32_bf16(wfr[0][kk], b, acc[rb][0], 0, 0, 0);
        acc[rb][1] = __builtin_amdgcn_mfma_f32_16x16x32_bf16(wfr[1][kk], b, acc[rb][1], 0, 0, 0);
      }
    }
    #pragma unroll
    for (int rb = 0; rb < 4; ++rb) {
      const int g = tile * 64 + rb * 16 + r16;
      if (g < N) {
        float* yrow = Y + (size_t)g * 128 + w * 32;
        #pragma unroll
        for (int cb = 0; cb < 2; ++cb)
          *(float4*)&yrow[cb * 16 + g16 * 4] =
              make_float4(acc[rb][cb][0], acc[rb][cb][1], acc[rb][cb][2], acc[rb][cb][3]);
      }
    }
    cur ^= 1;
  }
}

// Fused 3-phase scan (all blocks co-resident): block sums -> device-scope wait ->
// cross-block prefix + chunk exclusive scan.
__global__ __launch_bounds__(256) void scan_fused_kernel(
    const int* __restrict__ counts, int n, int* __restrict__ bsums,
    int* __restrict__ done, int* __restrict__ offsets)
{
  const int b = blockIdx.x, t = threadIdx.x;
  const int lane = t & 63, wid = t >> 6;
  const int idx = b * 256 + t;
  const int x = (idx < n) ? counts[idx] : 0;
  int v = x;
  #pragma unroll
  for (int off = 1; off < 64; off <<= 1) {
    const int tmp = __shfl_up(v, off);
    if (lane >= off) v += tmp;
  }
  __shared__ int wsum[4];
  __shared__ int base_s;
  if (lane == 63) wsum[wid] = v;
  __syncthreads();
  if (t == 0) {
    bsums[b] = wsum[0] + wsum[1] + wsum[2] + wsum[3];
    __threadfence();
    atomicAdd(done, 1);
    while (atomicAdd(done, 0) < (int)gridDim.x) {}
  }
  __syncthreads();
  __threadfence();
  int pre = (t < b) ? bsums[t] : 0;
  #pragma unroll
  for (int off = 1; off < 64; off <<= 1) pre += __shfl_xor(pre, off);
  __shared__ int pres[4];
  if (lane == 0) pres[wid] = pre;
  __syncthreads();
  if (t == 0) base_s = pres[0] + pres[1] + pres[2] + pres[3];
  __syncthreads();
  int wbase = 0;
  for (int p = 0; p < wid; ++p) wbase += wsum[p];
  if (idx < n) offsets[idx] = base_s + wbase + v - x;
}

// Destructive scatter: atomicAdd(&offsets[d],1) returns the absolute slot.
// Afterwards offsets[d] = start[d]+cnt[d] = start[d+1].
__global__ __launch_bounds__(256) void scatter_kernel(
    const int* __restrict__ ei, int E, int* __restrict__ offsets,
    int* __restrict__ csr_src)
{
  const int e = (blockIdx.x * 256 + threadIdx.x) * 4;
  if (e + 4 <= E) {
    const int4 s = *(const int4*)&ei[e];
    const int4 d = *(const int4*)&ei[E + e];
    int p;
    p = atomicAdd(&offsets[d.x], 1); csr_src[p] = s.x;
    p = atomicAdd(&offsets[d.y], 1); csr_src[p] = s.y;
    p = atomicAdd(&offsets[d.z], 1); csr_src[p] = s.z;
    p = atomicAdd(&offsets[d.w], 1); csr_src[p] = s.w;
  } else {
    for (int k = e; k < E; ++k) {
      const int d = ei[E + k];
      const int p = atomicAdd(&offsets[d], 1);
      csr_src[p] = ei[k];
    }
  }
}

// One wave per destination; lane=(eg=lane>>3, h=lane&7): full 16-dim dot per
// (edge,head). Row start = offsets[wave-1] (post-scatter), 0 for wave 0.
// End: butterfly reduce-scatter (14 shfls) -> all-lane coalesced store.
__global__ __launch_bounds__(256) void edge_attn_kernel(
    const unsigned short* __restrict__ qb, const unsigned short* __restrict__ kvb,
    const float* __restrict__ eb, const int* __restrict__ offsets,
    const int* __restrict__ counts, const int* __restrict__ csr_src,
    unsigned short* __restrict__ agg, int Ndst)
{
  const int wave = blockIdx.x * 4 + (threadIdx.x >> 6);
  if (wave >= Ndst) return;
  const int lane = threadIdx.x & 63;
  const int eg = lane >> 3, h = lane & 7;

  const uint4 q0 = *(const uint4*)&qb[(size_t)wave * 128 + h * 16];
  const uint4 q1 = *(const uint4*)&qb[(size_t)wave * 128 + h * 16 + 8];
  const float bias = eb[h];
  const int ro = (wave == 0) ? 0 : offsets[wave - 1];
  const int cnt = counts[wave];

  float acc[16];
  #pragma unroll
  for (int j = 0; j < 16; ++j) acc[j] = 0.f;
  float s = 0.f;

  int e = eg;
  bool act = e < cnt;
  int src = act ? csr_src[ro + e] : 0;
  const int iters = (cnt + 7) >> 3;
  for (int it = 0; it < iters; ++it) {
    const size_t base = (size_t)src * 256 + h * 16;
    const uint4 k0 = *(const uint4*)&kvb[base];
    const uint4 k1 = *(const uint4*)&kvb[base + 8];
    const uint4 v0 = *(const uint4*)&kvb[base + 128];
    const uint4 v1 = *(const uint4*)&kvb[base + 136];
    const int e2 = e + 8;                       // prefetch next src index
    const bool act2 = e2 < cnt;
    const int src2 = act2 ? csr_src[ro + e2] : 0;

    float p = 0.f;
    p = fmaf(bflo(q0.x), bflo(k0.x), p); p = fmaf(bfhi(q0.x), bfhi(k0.x), p);
    p = fmaf(bflo(q0.y), bflo(k0.y), p); p = fmaf(bfhi(q0.y), bfhi(k0.y), p);
    p = fmaf(bflo(q0.z), bflo(k0.z), p); p = fmaf(bfhi(q0.z), bfhi(k0.z), p);
    p = fmaf(bflo(q0.w), bflo(k0.w), p); p = fmaf(bfhi(q0.w), bfhi(k0.w), p);
    p = fmaf(bflo(q1.x), bflo(k1.x), p); p = fmaf(bfhi(q1.x), bfhi(k1.x), p);
    p = fmaf(bflo(q1.y), bflo(k1.y), p); p = fmaf(bfhi(q1.y), bfhi(k1.y), p);
    p = fmaf(bflo(q1.z), bflo(k1.z), p); p = fmaf(bfhi(q1.z), bfhi(k1.z), p);
    p = fmaf(bflo(q1.w), bflo(k1.w), p); p = fmaf(bfhi(q1.w), bfhi(k1.w), p);

    const float wgt = act ? __expf(fmaf(p, SCALE, bias)) : 0.f;
    s += wgt;
    acc[0]  = fmaf(wgt, bflo(v0.x), acc[0]);  acc[1]  = fmaf(wgt, bfhi(v0.x), acc[1]);
    acc[2]  = fmaf(wgt, bflo(v0.y), acc[2]);  acc[3]  = fmaf(wgt, bfhi(v0.y), acc[3]);
    acc[4]  = fmaf(wgt, bflo(v0.z), acc[4]);  acc[5]  = fmaf(wgt, bfhi(v0.z), acc[5]);
    acc[6]  = fmaf(wgt, bflo(v0.w), acc[6]);  acc[7]  = fmaf(wgt, bfhi(v0.w), acc[7]);
    acc[8]  = fmaf(wgt, bflo(v1.x), acc[8]);  acc[9]  = fmaf(wgt, bfhi(v1.x), acc[9]);
    acc[10] = fmaf(wgt, bflo(v1.y), acc[10]); acc[11] = fmaf(wgt, bfhi(v1.y), acc[11]);
    acc[12] = fmaf(wgt, bflo(v1.z), acc[12]); acc[13] = fmaf(wgt, bfhi(v1.z), acc[13]);
    acc[14] = fmaf(wgt, bflo(v1.w), acc[14]); acc[15] = fmaf(wgt, bfhi(v1.w), acc[15]);
    e = e2; act = act2; src = src2;
  }

  // reduce-scatter butterfly over eg (lanes ^8, ^16, ^32)
  const bool b0 = eg & 1, b1 = (eg >> 1) & 1, b2 = (eg >> 2) & 1;
  float r8[8];
  #pragma unroll
  for (int j = 0; j < 8; ++j) {
    const float keep = b0 ? acc[j + 8] : acc[j];
    const float send = b0 ? acc[j] : acc[j + 8];
    r8[j] = keep + __shfl_xor(send, 8);
  }
  float r4[4];
  #pragma unroll
  for (int j = 0; j < 4; ++j) {
    const float keep = b1 ? r8[j + 2] : r8[j];
    const float send = b1 ? r8[j] : r8[j + 2];
    r4[j] = keep + __shfl_xor(send, 16);
  }
  // NOTE: index math must pair the same elements as R8 (j+4/j+2 grouping);
  // keep R8's proven pairing exactly:
  float r4b[4];
  #pragma unroll
  for (int j = 0; j < 4; ++j) {
    const float keep = b1 ? r8[j + 4] : r8[j];
    const float send = b1 ? r8[j] : r8[j + 4];
    r4b[j] = keep + __shfl_xor(send, 16);
  }
  float r2[2];
  #pragma unroll
  for (int j = 0; j < 2; ++j) {
    const float keep = b2 ? r4b[j + 2] : r4b[j];
    const float send = b2 ? r4b[j] : r4b[j + 2];
    r2[j] = keep + __shfl_xor(send, 32);
  }
  s += __shfl_xor(s, 8); s += __shfl_xor(s, 16); s += __shfl_xor(s, 32);
  const float rs = 1.0f / (s + 1e-8f);
  const int col = h * 16 + (b0 ? 8 : 0) + (b1 ? 4 : 0) + (b2 ? 2 : 0);
  *(unsigned*)&agg[(size_t)wave * 128 + col] = pack_bf2(r2[0] * rs, r2[1] * rs);
}

extern "C" void kernel_launch(void* const* d_in, const int* in_sizes, int n_in,
                              void* d_out, int out_size, void* d_ws, size_t ws_size,
                              hipStream_t stream) {
  const float* x_src = (const float*)d_in[0];
  const float* x_dst = (const float*)d_in[1];
  const int*   ei    = (const int*)d_in[2];
  const float* Wq = (const float*)d_in[3];
  const float* bq = (const float*)d_in[4];
  const float* Wk = (const float*)d_in[5];
  const float* bk = (const float*)d_in[6];
  const float* Wv = (const float*)d_in[7];
  const float* bv = (const float*)d_in[8];
  const float* Wo = (const float*)d_in[9];
  const float* bo = (const float*)d_in[10];
  const float* eb = (const float*)d_in[11];

  const int Nsrc = in_sizes[0] / HIDDEN;
  const int Ndst = in_sizes[1] / HIDDEN;
  const int E    = in_sizes[2] / 2;

  char* w = (char*)d_ws;
  unsigned short* qb   = (unsigned short*)w; w += (size_t)Ndst * 128 * 2;
  unsigned short* kvb  = (unsigned short*)w; w += (size_t)Nsrc * 256 * 2;
  unsigned short* aggb = (unsigned short*)w; w += (size_t)Ndst * 128 * 2;
  unsigned short* Wb   = (unsigned short*)w; w += (size_t)4 * 16384 * 2;
  int* counts  = (int*)w; w += (size_t)Ndst * sizeof(int);        // zero region start
  int* done    = (int*)w; w += 64 * sizeof(int);                  // contiguous w/ counts
  int* offsets = (int*)w; w += (size_t)Ndst * sizeof(int);
  int* bsums   = (int*)w; w += 256 * sizeof(int);
  int* csr_src = (int*)w; w += (size_t)E * sizeof(int);

  dim3 blk256(256);
  const int nzero4 = (Ndst + 64 + 3) / 4;                         // counts+done, int4 units
  const int zblocks = (nzero4 + 255) / 256;
  init_kernel<<<32 + zblocks, blk256, 0, stream>>>(Wq, Wk, Wv, Wo, Wb, counts, nzero4);

  const int e4blocks = (E / 4 + 255) / 256;
  count_kernel<<<e4blocks, blk256, 0, stream>>>(ei, E, counts);

  qkv_gemm_kernel<<<3 * NB_G, blk256, 0, stream>>>(
      x_src, x_dst, Wb, bq, bk, bv, qb, kvb, Nsrc, Ndst);

  const int nb = (Ndst + 255) / 256;
  scan_fused_kernel<<<nb, blk256, 0, stream>>>(counts, Ndst, bsums, done, offsets);

  scatter_kernel<<<e4blocks, blk256, 0, stream>>>(ei, E, offsets, csr_src);

  const int ablocks = (Ndst + 3) / 4;
  edge_attn_kernel<<<ablocks, blk256, 0, stream>>>(qb, kvb, eb, offsets, counts,
                                                   csr_src, aggb, Ndst);

  out_gemm_kernel<<<NB_G, blk256, 0, stream>>>(aggb, Wb + 49152, bo, (float*)d_out, Ndst);
}

// Round 10
// 153.869 us; speedup vs baseline: 1.0235x; 1.0235x over previous
//
#include <hip/hip_runtime.h>
#include <math.h>

#define HIDDEN 128
#define SCALE 0.25f
#define NB_F 256   // blocks per GEMM flavor

typedef __attribute__((ext_vector_type(8))) short short8v;
typedef __attribute__((ext_vector_type(4))) float f32x4;

__device__ __forceinline__ unsigned short f2bf(float f) {
  const unsigned u = __float_as_uint(f);
  const unsigned r = u + 0x7fffu + ((u >> 16) & 1u);   // RNE
  return (unsigned short)(r >> 16);
}
__device__ __forceinline__ unsigned pack_bf2(float a, float b) {
  unsigned r;
  asm("v_cvt_pk_bf16_f32 %0, %1, %2" : "=v"(r) : "v"(a), "v"(b));
  return r;
}
__device__ __forceinline__ float bflo(unsigned u) { return __uint_as_float(u << 16); }
__device__ __forceinline__ float bfhi(unsigned u) { return __uint_as_float(u & 0xffff0000u); }

__device__ __forceinline__ void gload_lds16(const void* g, void* l) {
  __builtin_amdgcn_global_load_lds(
      (const __attribute__((address_space(1))) unsigned*)g,
      (__attribute__((address_space(3))) unsigned*)l, 16, 0, 0);
}

// blocks 0..31: fragment-ordered bf16 weights: chunk m*2048+(n*4+kk)*64+l ->
//   W_m[n*16+(l&15)][kk*32+(l>>4)*8 + 0..7].  blocks 32..: zero counts+done.
__global__ __launch_bounds__(256) void init_kernel(
    const float* __restrict__ W0, const float* __restrict__ W1,
    const float* __restrict__ W2, const float* __restrict__ W3,
    unsigned short* __restrict__ Wfrag, int* __restrict__ zero_base, int nzero4)
{
  if (blockIdx.x < 32) {
    const int chunk = blockIdx.x * 256 + threadIdx.x;
    const int m = chunk >> 11;
    const int rem = chunk & 2047;
    const int l = rem & 63;
    const int nkk = rem >> 6;
    const int n = nkk >> 2, kk = nkk & 3;
    const float* W = (m == 0) ? W0 : (m == 1) ? W1 : (m == 2) ? W2 : W3;
    const int row = n * 16 + (l & 15);
    const int k0 = kk * 32 + (l >> 4) * 8;
    const float4 v0 = *(const float4*)&W[row * 128 + k0];
    const float4 v1 = *(const float4*)&W[row * 128 + k0 + 4];
    uint4 o;
    o.x = (unsigned)f2bf(v0.x) | ((unsigned)f2bf(v0.y) << 16);
    o.y = (unsigned)f2bf(v0.z) | ((unsigned)f2bf(v0.w) << 16);
    o.z = (unsigned)f2bf(v1.x) | ((unsigned)f2bf(v1.y) << 16);
    o.w = (unsigned)f2bf(v1.z) | ((unsigned)f2bf(v1.w) << 16);
    *(uint4*)&Wfrag[(size_t)chunk * 8] = o;
  } else {
    const int idx4 = (blockIdx.x - 32) * 256 + threadIdx.x;
    if (idx4 < nzero4)
      *(int4*)&zero_base[idx4 * 4] = make_int4(0, 0, 0, 0);
  }
}

// Fused QKV projection + edge counting (independent block ranges).
// GEMM: wave = 16 rows x 128 cols. X B-fragments loaded DIRECTLY from global
// (lane l: X[base+(l&15)][kk*32+(l>>4)*8..+7], 2x float4); W staged once to LDS
// via global_load_lds, read conflict-free (lane-consecutive 16B). No barriers
// in the main loop; next-tile X loads issued right after cvt consumes current.
__global__ __launch_bounds__(256, 4) void qkv_count_kernel(
    const float* __restrict__ x_src, const float* __restrict__ x_dst,
    const unsigned short* __restrict__ Wfrag,
    const float* __restrict__ bq, const float* __restrict__ bk,
    const float* __restrict__ bv,
    unsigned short* __restrict__ qb, unsigned short* __restrict__ kvb,
    int Nsrc, int Ndst,
    const int* __restrict__ ei, int E, int* __restrict__ counts)
{
  __shared__ __align__(16) char WsB[32768];
  __shared__ float bias_s[128];
  const int t = threadIdx.x;
  const int bid = blockIdx.x;

  if (bid >= 3 * NB_F) {           // -------- count flavor --------
    const int e = ((bid - 3 * NB_F) * 256 + t) * 4;
    if (e + 4 <= E) {
      const int4 d = *(const int4*)&ei[E + e];
      atomicAdd(&counts[d.x], 1);
      atomicAdd(&counts[d.y], 1);
      atomicAdd(&counts[d.z], 1);
      atomicAdd(&counts[d.w], 1);
    } else {
      for (int k = e; k < E; ++k) atomicAdd(&counts[ei[E + k]], 1);
    }
    return;
  }

  const int flavor = bid / NB_F, sub = bid % NB_F;
  const float* X; const float* bias; const unsigned short* wbase;
  unsigned short* out; int ostride, ooff, N;
  if (flavor == 0)      { X = x_src; bias = bk; wbase = Wfrag + 16384; out = kvb; ostride = 256; ooff = 0;   N = Nsrc; }
  else if (flavor == 1) { X = x_src; bias = bv; wbase = Wfrag + 32768; out = kvb; ostride = 256; ooff = 128; N = Nsrc; }
  else                  { X = x_dst; bias = bq; wbase = Wfrag;         out = qb;  ostride = 128; ooff = 0;   N = Ndst; }

  #pragma unroll
  for (int it = 0; it < 8; ++it) {
    const int off = (it * 256 + t) * 16;
    gload_lds16((const char*)wbase + off, WsB + off);
  }
  if (t < 128) bias_s[t] = bias[t];
  asm volatile("s_waitcnt vmcnt(0)" ::: "memory");
  __syncthreads();

  const int l = t & 63, w = t >> 6;
  const int r16 = l & 15, g16 = l >> 4;
  const int ntiles = (N + 15) >> 4;
  const int stride = NB_F * 4;
  int tile = sub * 4 + w;
  if (tile >= ntiles) return;

  float4 xv[8];
  {
    const int row = tile * 16 + r16;
    const bool valid = row < N;
    const float* xp = X + (size_t)row * 128 + g16 * 8;
    #pragma unroll
    for (int kk = 0; kk < 4; ++kk) {
      xv[2 * kk]     = valid ? *(const float4*)(xp + kk * 32)     : make_float4(0.f, 0.f, 0.f, 0.f);
      xv[2 * kk + 1] = valid ? *(const float4*)(xp + kk * 32 + 4) : make_float4(0.f, 0.f, 0.f, 0.f);
    }
  }
  for (; tile < ntiles; tile += stride) {
    const int nt = tile + stride;
    short8v a[4];
    #pragma unroll
    for (int kk = 0; kk < 4; ++kk) {
      uint4 u;
      u.x = pack_bf2(xv[2 * kk].x,     xv[2 * kk].y);
      u.y = pack_bf2(xv[2 * kk].z,     xv[2 * kk].w);
      u.z = pack_bf2(xv[2 * kk + 1].x, xv[2 * kk + 1].y);
      u.w = pack_bf2(xv[2 * kk + 1].z, xv[2 * kk + 1].w);
      a[kk] = *(short8v*)&u;
    }
    if (nt < ntiles) {               // prefetch next tile (WAR-safe: a[] holds data)
      const int row = nt * 16 + r16;
      const bool valid = row < N;
      const float* xp = X + (size_t)row * 128 + g16 * 8;
      #pragma unroll
      for (int kk = 0; kk < 4; ++kk) {
        xv[2 * kk]     = valid ? *(const float4*)(xp + kk * 32)     : make_float4(0.f, 0.f, 0.f, 0.f);
        xv[2 * kk + 1] = valid ? *(const float4*)(xp + kk * 32 + 4) : make_float4(0.f, 0.f, 0.f, 0.f);
      }
    }
    f32x4 acc[8];
    #pragma unroll
    for (int n = 0; n < 8; ++n) acc[n] = (f32x4){0.f, 0.f, 0.f, 0.f};
    #pragma unroll
    for (int kk = 0; kk < 4; ++kk) {
      #pragma unroll
      for (int n = 0; n < 8; ++n) {
        const short8v wf = *(const short8v*)&WsB[((n * 4 + kk) * 64 + l) * 16];
        acc[n] = __builtin_amdgcn_mfma_f32_16x16x32_bf16(wf, a[kk], acc[n], 0, 0, 0);
      }
    }
    const int row = tile * 16 + r16;   // D: row=feature (n*16+g16*4+r), col=X-row (r16)
    if (row < N) {
      unsigned short* orow = out + (size_t)row * ostride + ooff;
      #pragma unroll
      for (int n = 0; n < 8; ++n) {
        const float4 bb = *(const float4*)&bias_s[n * 16 + g16 * 4];
        uint2 o;
        o.x = pack_bf2(acc[n][0] + bb.x, acc[n][1] + bb.y);
        o.y = pack_bf2(acc[n][2] + bb.z, acc[n][3] + bb.w);
        *(uint2*)&orow[n * 16 + g16 * 4] = o;
      }
    }
  }
}

// Output projection: same structure; agg is bf16 so B-fragments load directly
// (one uint4 per kk, no cvt); f32 float4 epilogue.
__global__ __launch_bounds__(256, 4) void out_gemm_kernel(
    const unsigned short* __restrict__ agg, const unsigned short* __restrict__ Wfrag_o,
    const float* __restrict__ bo, float* __restrict__ Y, int N)
{
  __shared__ __align__(16) char WsB[32768];
  __shared__ float bias_s[128];
  const int t = threadIdx.x;
  #pragma unroll
  for (int it = 0; it < 8; ++it) {
    const int off = (it * 256 + t) * 16;
    gload_lds16((const char*)Wfrag_o + off, WsB + off);
  }
  if (t < 128) bias_s[t] = bo[t];
  asm volatile("s_waitcnt vmcnt(0)" ::: "memory");
  __syncthreads();

  const int l = t & 63, w = t >> 6;
  const int r16 = l & 15, g16 = l >> 4;
  const int ntiles = (N + 15) >> 4;
  const int stride = NB_F * 4;
  int tile = blockIdx.x * 4 + w;
  if (tile >= ntiles) return;

  uint4 av[4];
  {
    const int row = tile * 16 + r16;
    const bool valid = row < N;
    const unsigned short* ap = agg + (size_t)row * 128 + g16 * 8;
    #pragma unroll
    for (int kk = 0; kk < 4; ++kk)
      av[kk] = valid ? *(const uint4*)(ap + kk * 32) : make_uint4(0, 0, 0, 0);
  }
  for (; tile < ntiles; tile += stride) {
    const int nt = tile + stride;
    short8v a[4];
    #pragma unroll
    for (int kk = 0; kk < 4; ++kk) a[kk] = *(short8v*)&av[kk];
    if (nt < ntiles) {
      const int row = nt * 16 + r16;
      const bool valid = row < N;
      const unsigned short* ap = agg + (size_t)row * 128 + g16 * 8;
      #pragma unroll
      for (int kk = 0; kk < 4; ++kk)
        av[kk] = valid ? *(const uint4*)(ap + kk * 32) : make_uint4(0, 0, 0, 0);
    }
    f32x4 acc[8];
    #pragma unroll
    for (int n = 0; n < 8; ++n) acc[n] = (f32x4){0.f, 0.f, 0.f, 0.f};
    #pragma unroll
    for (int kk = 0; kk < 4; ++kk) {
      #pragma unroll
      for (int n = 0; n < 8; ++n) {
        const short8v wf = *(const short8v*)&WsB[((n * 4 + kk) * 64 + l) * 16];
        acc[n] = __builtin_amdgcn_mfma_f32_16x16x32_bf16(wf, a[kk], acc[n], 0, 0, 0);
      }
    }
    const int row = tile * 16 + r16;
    if (row < N) {
      float* yrow = Y + (size_t)row * 128;
      #pragma unroll
      for (int n = 0; n < 8; ++n) {
        const float4 bb = *(const float4*)&bias_s[n * 16 + g16 * 4];
        *(float4*)&yrow[n * 16 + g16 * 4] =
            make_float4(acc[n][0] + bb.x, acc[n][1] + bb.y, acc[n][2] + bb.z, acc[n][3] + bb.w);
      }
    }
  }
}

// Fused 3-phase scan (all blocks co-resident): block sums -> device-scope wait ->
// cross-block prefix + chunk exclusive scan.
__global__ __launch_bounds__(256) void scan_fused_kernel(
    const int* __restrict__ counts, int n, int* __restrict__ bsums,
    int* __restrict__ done, int* __restrict__ offsets)
{
  const int b = blockIdx.x, t = threadIdx.x;
  const int lane = t & 63, wid = t >> 6;
  const int idx = b * 256 + t;
  const int x = (idx < n) ? counts[idx] : 0;
  int v = x;
  #pragma unroll
  for (int off = 1; off < 64; off <<= 1) {
    const int tmp = __shfl_up(v, off);
    if (lane >= off) v += tmp;
  }
  __shared__ int wsum[4];
  __shared__ int base_s;
  if (lane == 63) wsum[wid] = v;
  __syncthreads();
  if (t == 0) {
    bsums[b] = wsum[0] + wsum[1] + wsum[2] + wsum[3];
    __threadfence();
    atomicAdd(done, 1);
    while (atomicAdd(done, 0) < (int)gridDim.x) {}
  }
  __syncthreads();
  __threadfence();
  int pre = (t < b) ? bsums[t] : 0;
  #pragma unroll
  for (int off = 1; off < 64; off <<= 1) pre += __shfl_xor(pre, off);
  __shared__ int pres[4];
  if (lane == 0) pres[wid] = pre;
  __syncthreads();
  if (t == 0) base_s = pres[0] + pres[1] + pres[2] + pres[3];
  __syncthreads();
  int wbase = 0;
  for (int p = 0; p < wid; ++p) wbase += wsum[p];
  if (idx < n) offsets[idx] = base_s + wbase + v - x;
}

// Destructive scatter: atomicAdd(&offsets[d],1) returns the absolute slot.
// Afterwards offsets[d] = start[d+1].
__global__ __launch_bounds__(256) void scatter_kernel(
    const int* __restrict__ ei, int E, int* __restrict__ offsets,
    int* __restrict__ csr_src)
{
  const int e = (blockIdx.x * 256 + threadIdx.x) * 4;
  if (e + 4 <= E) {
    const int4 s = *(const int4*)&ei[e];
    const int4 d = *(const int4*)&ei[E + e];
    int p;
    p = atomicAdd(&offsets[d.x], 1); csr_src[p] = s.x;
    p = atomicAdd(&offsets[d.y], 1); csr_src[p] = s.y;
    p = atomicAdd(&offsets[d.z], 1); csr_src[p] = s.z;
    p = atomicAdd(&offsets[d.w], 1); csr_src[p] = s.w;
  } else {
    for (int k = e; k < E; ++k) {
      const int d = ei[E + k];
      const int p = atomicAdd(&offsets[d], 1);
      csr_src[p] = ei[k];
    }
  }
}

// One wave per destination; lane=(eg=lane>>3, h=lane&7): full 16-dim dot per
// (edge,head). Row start = offsets[wave-1] (post-scatter), 0 for wave 0.
// End: butterfly reduce-scatter -> all-lane coalesced store.
__global__ __launch_bounds__(256) void edge_attn_kernel(
    const unsigned short* __restrict__ qb, const unsigned short* __restrict__ kvb,
    const float* __restrict__ eb, const int* __restrict__ offsets,
    const int* __restrict__ counts, const int* __restrict__ csr_src,
    unsigned short* __restrict__ agg, int Ndst)
{
  const int wave = blockIdx.x * 4 + (threadIdx.x >> 6);
  if (wave >= Ndst) return;
  const int lane = threadIdx.x & 63;
  const int eg = lane >> 3, h = lane & 7;

  const uint4 q0 = *(const uint4*)&qb[(size_t)wave * 128 + h * 16];
  const uint4 q1 = *(const uint4*)&qb[(size_t)wave * 128 + h * 16 + 8];
  const float bias = eb[h];
  const int ro = (wave == 0) ? 0 : offsets[wave - 1];
  const int cnt = counts[wave];

  float acc[16];
  #pragma unroll
  for (int j = 0; j < 16; ++j) acc[j] = 0.f;
  float s = 0.f;

  int e = eg;
  bool act = e < cnt;
  int src = act ? csr_src[ro + e] : 0;
  const int iters = (cnt + 7) >> 3;
  for (int it = 0; it < iters; ++it) {
    const size_t base = (size_t)src * 256 + h * 16;
    const uint4 k0 = *(const uint4*)&kvb[base];
    const uint4 k1 = *(const uint4*)&kvb[base + 8];
    const uint4 v0 = *(const uint4*)&kvb[base + 128];
    const uint4 v1 = *(const uint4*)&kvb[base + 136];
    const int e2 = e + 8;
    const bool act2 = e2 < cnt;
    const int src2 = act2 ? csr_src[ro + e2] : 0;

    float p = 0.f;
    p = fmaf(bflo(q0.x), bflo(k0.x), p); p = fmaf(bfhi(q0.x), bfhi(k0.x), p);
    p = fmaf(bflo(q0.y), bflo(k0.y), p); p = fmaf(bfhi(q0.y), bfhi(k0.y), p);
    p = fmaf(bflo(q0.z), bflo(k0.z), p); p = fmaf(bfhi(q0.z), bfhi(k0.z), p);
    p = fmaf(bflo(q0.w), bflo(k0.w), p); p = fmaf(bfhi(q0.w), bfhi(k0.w), p);
    p = fmaf(bflo(q1.x), bflo(k1.x), p); p = fmaf(bfhi(q1.x), bfhi(k1.x), p);
    p = fmaf(bflo(q1.y), bflo(k1.y), p); p = fmaf(bfhi(q1.y), bfhi(k1.y), p);
    p = fmaf(bflo(q1.z), bflo(k1.z), p); p = fmaf(bfhi(q1.z), bfhi(k1.z), p);
    p = fmaf(bflo(q1.w), bflo(k1.w), p); p = fmaf(bfhi(q1.w), bfhi(k1.w), p);

    const float wgt = act ? __expf(fmaf(p, SCALE, bias)) : 0.f;
    s += wgt;
    acc[0]  = fmaf(wgt, bflo(v0.x), acc[0]);  acc[1]  = fmaf(wgt, bfhi(v0.x), acc[1]);
    acc[2]  = fmaf(wgt, bflo(v0.y), acc[2]);  acc[3]  = fmaf(wgt, bfhi(v0.y), acc[3]);
    acc[4]  = fmaf(wgt, bflo(v0.z), acc[4]);  acc[5]  = fmaf(wgt, bfhi(v0.z), acc[5]);
    acc[6]  = fmaf(wgt, bflo(v0.w), acc[6]);  acc[7]  = fmaf(wgt, bfhi(v0.w), acc[7]);
    acc[8]  = fmaf(wgt, bflo(v1.x), acc[8]);  acc[9]  = fmaf(wgt, bfhi(v1.x), acc[9]);
    acc[10] = fmaf(wgt, bflo(v1.y), acc[10]); acc[11] = fmaf(wgt, bfhi(v1.y), acc[11]);
    acc[12] = fmaf(wgt, bflo(v1.z), acc[12]); acc[13] = fmaf(wgt, bfhi(v1.z), acc[13]);
    acc[14] = fmaf(wgt, bflo(v1.w), acc[14]); acc[15] = fmaf(wgt, bfhi(v1.w), acc[15]);
    e = e2; act = act2; src = src2;
  }

  // reduce-scatter butterfly over eg (lanes ^8, ^16, ^32) -- R8-proven pairing
  const bool b0 = eg & 1, b1 = (eg >> 1) & 1, b2 = (eg >> 2) & 1;
  float r8[8];
  #pragma unroll
  for (int j = 0; j < 8; ++j) {
    const float keep = b0 ? acc[j + 8] : acc[j];
    const float send = b0 ? acc[j] : acc[j + 8];
    r8[j] = keep + __shfl_xor(send, 8);
  }
  float r4[4];
  #pragma unroll
  for (int j = 0; j < 4; ++j) {
    const float keep = b1 ? r8[j + 4] : r8[j];
    const float send = b1 ? r8[j] : r8[j + 4];
    r4[j] = keep + __shfl_xor(send, 16);
  }
  float r2[2];
  #pragma unroll
  for (int j = 0; j < 2; ++j) {
    const float keep = b2 ? r4[j + 2] : r4[j];
    const float send = b2 ? r4[j] : r4[j + 2];
    r2[j] = keep + __shfl_xor(send, 32);
  }
  s += __shfl_xor(s, 8); s += __shfl_xor(s, 16); s += __shfl_xor(s, 32);
  const float rs = 1.0f / (s + 1e-8f);
  const int col = h * 16 + (b0 ? 8 : 0) + (b1 ? 4 : 0) + (b2 ? 2 : 0);
  *(unsigned*)&agg[(size_t)wave * 128 + col] = pack_bf2(r2[0] * rs, r2[1] * rs);
}

extern "C" void kernel_launch(void* const* d_in, const int* in_sizes, int n_in,
                              void* d_out, int out_size, void* d_ws, size_t ws_size,
                              hipStream_t stream) {
  const float* x_src = (const float*)d_in[0];
  const float* x_dst = (const float*)d_in[1];
  const int*   ei    = (const int*)d_in[2];
  const float* Wq = (const float*)d_in[3];
  const float* bq = (const float*)d_in[4];
  const float* Wk = (const float*)d_in[5];
  const float* bk = (const float*)d_in[6];
  const float* Wv = (const float*)d_in[7];
  const float* bv = (const float*)d_in[8];
  const float* Wo = (const float*)d_in[9];
  const float* bo = (const float*)d_in[10];
  const float* eb = (const float*)d_in[11];

  const int Nsrc = in_sizes[0] / HIDDEN;
  const int Ndst = in_sizes[1] / HIDDEN;
  const int E    = in_sizes[2] / 2;

  char* w = (char*)d_ws;
  unsigned short* qb   = (unsigned short*)w; w += (size_t)Ndst * 128 * 2;
  unsigned short* kvb  = (unsigned short*)w; w += (size_t)Nsrc * 256 * 2;
  unsigned short* aggb = (unsigned short*)w; w += (size_t)Ndst * 128 * 2;
  unsigned short* Wb   = (unsigned short*)w; w += (size_t)4 * 16384 * 2;
  int* counts  = (int*)w; w += (size_t)Ndst * sizeof(int);        // zero region start
  int* done    = (int*)w; w += 64 * sizeof(int);                  // contiguous w/ counts
  int* offsets = (int*)w; w += (size_t)Ndst * sizeof(int);
  int* bsums   = (int*)w; w += 256 * sizeof(int);
  int* csr_src = (int*)w; w += (size_t)E * sizeof(int);

  dim3 blk256(256);
  const int nzero4 = (Ndst + 64 + 3) / 4;
  const int zblocks = (nzero4 + 255) / 256;
  init_kernel<<<32 + zblocks, blk256, 0, stream>>>(Wq, Wk, Wv, Wo, Wb, counts, nzero4);

  const int e4blocks = (E / 4 + 255) / 256;
  qkv_count_kernel<<<3 * NB_F + e4blocks, blk256, 0, stream>>>(
      x_src, x_dst, Wb, bq, bk, bv, qb, kvb, Nsrc, Ndst, ei, E, counts);

  const int nb = (Ndst + 255) / 256;
  scan_fused_kernel<<<nb, blk256, 0, stream>>>(counts, Ndst, bsums, done, offsets);

  scatter_kernel<<<e4blocks, blk256, 0, stream>>>(ei, E, offsets, csr_src);

  const int ablocks = (Ndst + 3) / 4;
  edge_attn_kernel<<<ablocks, blk256, 0, stream>>>(qb, kvb, eb, offsets, counts,
                                                   csr_src, aggb, Ndst);

  out_gemm_kernel<<<NB_F, blk256, 0, stream>>>(aggb, Wb + 49152, bo, (float*)d_out, Ndst);
}